// Round 9
// baseline (96.284 us; speedup 1.0000x reference)
//
#include <hip/hip_runtime.h>
#include <math.h>

// Problem constants
#define BATCH 32
#define HHWW  12544          // 112*112
#define CH    96
#define CH4   24             // CH/4
#define CR    24             // reduced channels
#define NBLK  28             // slices per batch
#define ROWS_PER_BLK (HHWW / NBLK)   // 448
#define RDIM  16             // row-threads per block

typedef float f32x4 __attribute__((ext_vector_type(4)));

// ws layout:
//   partial [BATCH][NBLK][CH] f32 : 344064 B
//   gate    [BATCH][CH]       f32 :  12288 B (offset 344064)
//   counter [BATCH]           u32 :    128 B (offset 356352)

// ---------------------------------------------------------------------------
// Kernel 1: pool partials + elected-block gate.
// grid = (NBLK, BATCH) = 896 blocks, block (24,16) = 384 threads.
//
// Coherence design (the R7 lesson): the ticket atomic uses RELEASE only —
// the release emits an L2 writeback (cheap: dirty bytes are a few KB of
// partials). R7's ACQ_REL added an L2 *invalidate* per block (896 of them),
// each dropping the whole XCD's streaming locality -> 600 GB/s collapse.
// Here only the 32 elected blocks (one per batch) pay one ACQUIRE each,
// after pooling traffic is essentially done.
//
// Election: counter is never initialized/reset; any 28 consecutive ticket
// values contain (old+1) % 28 == 0 exactly once -> exactly one block per
// batch per launch computes the gate. Proven correct in R5/R7.
// ---------------------------------------------------------------------------
__global__ void __launch_bounds__(384)
se_pool_gate(const f32x4* __restrict__ in,
             const float* __restrict__ w_reduce,  // [CH][CR]
             const float* __restrict__ b_reduce,  // [CR]
             const float* __restrict__ w_expand,  // [CR][CH]
             const float* __restrict__ b_expand,  // [CH]
             float* __restrict__ partial,         // [BATCH][NBLK][CH]
             float* __restrict__ gate,            // [BATCH][CH]
             unsigned int* __restrict__ counter)  // [BATCH]
{
    const int blk = blockIdx.x;   // 0..27 slice
    const int b   = blockIdx.y;   // 0..31 batch
    const int q   = threadIdx.x;  // 0..23 channel quad
    const int r   = threadIdx.y;  // 0..15 row lane
    const int tid = q + CH4 * r;  // 0..383

    const size_t boff = (size_t)b * (HHWW * CH4);
    const int row0 = blk * ROWS_PER_BLK;

    // ---- pooling partial sums (proven streaming body) ----
    f32x4 acc = (f32x4)(0.f);
    #pragma unroll 4
    for (int row = row0 + r; row < row0 + ROWS_PER_BLK; row += RDIM)
        acc += in[boff + (size_t)row * CH4 + q];

    __shared__ f32x4 sdata[RDIM][CH4];
    sdata[r][q] = acc;
    __syncthreads();
    if (r == 0) {
        f32x4 s = sdata[0][q];
        #pragma unroll
        for (int k = 1; k < RDIM; ++k) s += sdata[k][q];
        ((f32x4*)partial)[((size_t)b * NBLK + blk) * CH4 + q] = s;
    }
    __syncthreads();

    // ---- ticket election: RELEASE only (wbl2, no inv) ----
    __shared__ int isLast;
    if (tid == 0) {
        unsigned int old = __hip_atomic_fetch_add(&counter[b], 1u,
                                                  __ATOMIC_RELEASE,
                                                  __HIP_MEMORY_SCOPE_AGENT);
        int elected = (((old + 1u) % NBLK) == 0u) ? 1 : 0;
        if (elected) {
            // one ACQUIRE per batch (32 total): invalidate THIS XCD's caches
            // so the partial reads below see other XCDs' written-back data.
            (void)__hip_atomic_load(&counter[b], __ATOMIC_ACQUIRE,
                                    __HIP_MEMORY_SCOPE_AGENT);
        }
        isLast = elected;
    }
    __syncthreads();

    if (isLast) {
        __shared__ float pooled[CH];
        __shared__ float hsw[CR];

        if (tid < CH) {
            float s = 0.f;
            #pragma unroll
            for (int k = 0; k < NBLK; ++k)
                s += partial[((size_t)b * NBLK + k) * CH + tid];
            pooled[tid] = s * (1.0f / (float)HHWW);
        }
        __syncthreads();
        if (tid < CR) {
            float h = b_reduce[tid];
            #pragma unroll
            for (int i = 0; i < CH; ++i)
                h += pooled[i] * w_reduce[i * CR + tid];
            hsw[tid] = h / (1.0f + expf(-h));   // swish
        }
        __syncthreads();
        if (tid < CH) {
            float g = b_expand[tid];
            #pragma unroll
            for (int j = 0; j < CR; ++j)
                g += hsw[j] * w_expand[j * CH + tid];
            gate[(size_t)b * CH + tid] = 1.0f / (1.0f + expf(-g));
        }
    }
}

// ---------------------------------------------------------------------------
// Kernel 2: scale (verbatim R2-proven). grid (49, BATCH), block 256,
// 24 float4/thread; gate quads register-cached via period-3 cycle;
// coherent NT stores.
// ---------------------------------------------------------------------------
__global__ void __launch_bounds__(256)
se_scale(const f32x4* __restrict__ in,
         const float* __restrict__ gate,   // [BATCH][CH]
         f32x4* __restrict__ out)
{
    const int b = blockIdx.y;
    const int t = threadIdx.x;

    const int q0 = t % CH4;
    const int q1 = (q0 + 16) % CH4;
    const int q2 = (q0 + 8) % CH4;
    const f32x4* g4 = (const f32x4*)(gate + (size_t)b * CH);
    const f32x4 g0 = g4[q0];
    const f32x4 g1 = g4[q1];
    const f32x4 g2 = g4[q2];

    const size_t boff = (size_t)b * (HHWW * CH4);
    int idx = blockIdx.x * 6144 + t;
    #pragma unroll
    for (int k = 0; k < 24; k += 3) {
        f32x4 v0 = in[boff + idx];
        f32x4 v1 = in[boff + idx + 256];
        f32x4 v2 = in[boff + idx + 512];
        __builtin_nontemporal_store(v0 * g0, &out[boff + idx]);
        __builtin_nontemporal_store(v1 * g1, &out[boff + idx + 256]);
        __builtin_nontemporal_store(v2 * g2, &out[boff + idx + 512]);
        idx += 768;
    }
}

extern "C" void kernel_launch(void* const* d_in, const int* in_sizes, int n_in,
                              void* d_out, int out_size, void* d_ws, size_t ws_size,
                              hipStream_t stream) {
    const f32x4* in       = (const f32x4*)d_in[0];
    const float* w_reduce = (const float*)d_in[1];
    const float* b_reduce = (const float*)d_in[2];
    const float* w_expand = (const float*)d_in[3];
    const float* b_expand = (const float*)d_in[4];
    f32x4* out = (f32x4*)d_out;

    char* ws = (char*)d_ws;
    float*        partial = (float*)ws;                    // 344064 B
    float*        gate    = (float*)(ws + 344064);         //  12288 B
    unsigned int* counter = (unsigned int*)(ws + 356352);  //    128 B

    dim3 gridP(NBLK, BATCH);    // 896 blocks
    dim3 blockP(CH4, RDIM);     // 384 threads
    se_pool_gate<<<gridP, blockP, 0, stream>>>(in, w_reduce, b_reduce,
                                               w_expand, b_expand,
                                               partial, gate, counter);

    dim3 gridS(49, BATCH);      // 1568 blocks
    se_scale<<<gridS, 256, 0, stream>>>(in, gate, out);
}